// Round 3
// baseline (725.284 us; speedup 1.0000x reference)
//
#include <hip/hip_runtime.h>
#include <hip/hip_bf16.h>

// Problem constants (shapes fixed by the reference; N/E derived at launch).
#define IN_DIM 256
#define OUT_DIM 128
#define SLOPE 0.1f

// ---------------------------------------------------------------------------
// GEMM: emb[N][128] = node_feats[N][256] @ W[128][256]^T + b
// Tile: BM=128 rows x BN=128 cols, BK=32. 256 threads, each 8x8 accumulators.
// Epilogue additionally computes a1[r] = emb[r].a[0:128], a2[r] = emb[r].a[128:256]
// (each block owns the full 128-col row, so the dot is block-local).
// ---------------------------------------------------------------------------
#define BM 128
#define BN 128
#define BK 32

__global__ __launch_bounds__(256) void gemm_kernel(
    const float* __restrict__ A,     // [N][256]
    const float* __restrict__ W,     // [128][256]
    const float* __restrict__ bias,  // [128]
    const float* __restrict__ avec,  // [256]
    float* __restrict__ emb,         // [N][128]
    float* __restrict__ a1,          // [N]
    float* __restrict__ a2,          // [N]
    int N) {
  __shared__ float As[BM][BK + 1];   // pad: conflict-free column reads
  __shared__ float Bs[BK][BN + 4];

  const int tid = threadIdx.x;
  const int row0 = blockIdx.x * BM;
  const int tx = tid & 15;           // 16 col groups x 8 cols
  const int ty = tid >> 4;           // 16 row groups x 8 rows

  float acc[8][8] = {};

  for (int k0 = 0; k0 < IN_DIM; k0 += BK) {
    // Load A tile: 128 rows x 32 cols = 1024 float4s, 4 per thread.
#pragma unroll
    for (int i = 0; i < 4; ++i) {
      int f = tid + i * 256;
      int r = f >> 3;
      int c4 = (f & 7) * 4;
      float4 v = make_float4(0.f, 0.f, 0.f, 0.f);
      if (row0 + r < N)
        v = *(const float4*)&A[(size_t)(row0 + r) * IN_DIM + k0 + c4];
      As[r][c4 + 0] = v.x; As[r][c4 + 1] = v.y;
      As[r][c4 + 2] = v.z; As[r][c4 + 3] = v.w;
    }
    // Load B tile transposed: Bs[k][n] = W[n][k0+k].
#pragma unroll
    for (int i = 0; i < 4; ++i) {
      int f = tid + i * 256;
      int nn = f >> 3;
      int c4 = (f & 7) * 4;
      float4 v = *(const float4*)&W[(size_t)nn * IN_DIM + k0 + c4];
      Bs[c4 + 0][nn] = v.x; Bs[c4 + 1][nn] = v.y;
      Bs[c4 + 2][nn] = v.z; Bs[c4 + 3][nn] = v.w;
    }
    __syncthreads();

#pragma unroll
    for (int k = 0; k < BK; ++k) {
      float a_[8], b_[8];
#pragma unroll
      for (int j = 0; j < 8; ++j) a_[j] = As[ty * 8 + j][k];
#pragma unroll
      for (int i = 0; i < 8; ++i) b_[i] = Bs[k][tx * 8 + i];
#pragma unroll
      for (int j = 0; j < 8; ++j)
#pragma unroll
        for (int i = 0; i < 8; ++i) acc[j][i] += a_[j] * b_[i];
    }
    __syncthreads();
  }

  // Epilogue: add bias, store float4, and accumulate per-thread partials of
  // the attention dots p1[j] = sum_c emb[r][c]*avec[c], p2[j] with avec[128+c].
  float p1[8], p2[8];
#pragma unroll
  for (int j = 0; j < 8; ++j) { p1[j] = 0.f; p2[j] = 0.f; }

#pragma unroll
  for (int j = 0; j < 8; ++j) {
    int r = row0 + ty * 8 + j;
    if (r < N) {
#pragma unroll
      for (int i = 0; i < 8; i += 4) {
        int c = tx * 8 + i;
        float4 v;
        v.x = acc[j][i + 0] + bias[c + 0];
        v.y = acc[j][i + 1] + bias[c + 1];
        v.z = acc[j][i + 2] + bias[c + 2];
        v.w = acc[j][i + 3] + bias[c + 3];
        *(float4*)&emb[(size_t)r * OUT_DIM + c] = v;
        p1[j] += v.x * avec[c + 0] + v.y * avec[c + 1] +
                 v.z * avec[c + 2] + v.w * avec[c + 3];
        p2[j] += v.x * avec[OUT_DIM + c + 0] + v.y * avec[OUT_DIM + c + 1] +
                 v.z * avec[OUT_DIM + c + 2] + v.w * avec[OUT_DIM + c + 3];
      }
    }
  }
  // Reduce across the 16 lanes sharing a row (tx = lane&15; xor 1,2,4,8 stays
  // within the aligned 16-lane group).
#pragma unroll
  for (int j = 0; j < 8; ++j) {
#pragma unroll
    for (int d = 1; d < 16; d <<= 1) {
      p1[j] += __shfl_xor(p1[j], d, 64);
      p2[j] += __shfl_xor(p2[j], d, 64);
    }
  }
  if (tx == 0) {
#pragma unroll
    for (int j = 0; j < 8; ++j) {
      int r = row0 + ty * 8 + j;
      if (r < N) { a1[r] = p1[j]; a2[r] = p2[j]; }
    }
  }
}

// ---------------------------------------------------------------------------
// CSR build: histogram of src, exclusive scan, cursor scatter of dst.
// ---------------------------------------------------------------------------
__global__ void hist_kernel(const int* __restrict__ src, int* __restrict__ deg,
                            int E) {
  int i = blockIdx.x * blockDim.x + threadIdx.x;
  if (i < E) atomicAdd(&deg[src[i]], 1);
}

// Single-workgroup chunked scan (1024 threads). N=100K -> ~98 chunks.
__global__ __launch_bounds__(1024) void scan_kernel(
    const int* __restrict__ deg, int* __restrict__ offset,
    int* __restrict__ pos, int N) {
  __shared__ int tmp[16];
  __shared__ int carry;
  const int tid = threadIdx.x;
  const int lane = tid & 63;
  const int wave = tid >> 6;
  if (tid == 0) carry = 0;
  __syncthreads();
  for (int base = 0; base < N; base += 1024) {
    int i = base + tid;
    int v = (i < N) ? deg[i] : 0;
    int x = v;
#pragma unroll
    for (int d = 1; d < 64; d <<= 1) {
      int y = __shfl_up(x, d, 64);
      if (lane >= d) x += y;
    }
    if (lane == 63) tmp[wave] = x;
    __syncthreads();
    if (tid < 16) {
      int wv = tmp[tid];
#pragma unroll
      for (int d = 1; d < 16; d <<= 1) {
        int y = __shfl_up(wv, d, 16);
        if (tid >= d) wv += y;
      }
      tmp[tid] = wv;  // inclusive wave totals
    }
    __syncthreads();
    int waveoff = (wave == 0) ? 0 : tmp[wave - 1];
    int excl = carry + waveoff + x - v;
    if (i < N) { offset[i] = excl; pos[i] = excl; }
    __syncthreads();
    if (tid == 0) carry += tmp[15];
    __syncthreads();
  }
}

__global__ void scatter_kernel(const int* __restrict__ src,
                               const int* __restrict__ dst,
                               int* __restrict__ pos,
                               int* __restrict__ tsorted, int E) {
  int i = blockIdx.x * blockDim.x + threadIdx.x;
  if (i < E) {
    int p = atomicAdd(&pos[src[i]], 1);
    tsorted[p] = dst[i];
  }
}

// ---------------------------------------------------------------------------
// Aggregation: one wave per node, lane holds 2 of 128 cols (float2 = 512B/wave
// per gathered row). Scores recomputed on the fly from a1/a2; self-loop
// handled inline. Edge index stream pipelined 2 deep to hide the
// tsorted->a2->emb dependent-load chain.
// ---------------------------------------------------------------------------
__global__ __launch_bounds__(256) void aggregate_kernel(
    const float* __restrict__ emb, const float* __restrict__ a1,
    const float* __restrict__ a2, const int* __restrict__ offset,
    const int* __restrict__ deg, const int* __restrict__ tsorted,
    float* __restrict__ out, int N) {
  int n = (int)((blockIdx.x * (size_t)blockDim.x + threadIdx.x) >> 6);
  int lane = threadIdx.x & 63;
  if (n >= N) return;

  const float as = a1[n];
  float2 acc;
  float den;
  {  // self loop (t = n)
    float logit = as + a2[n];
    float sc = expf(logit > 0.f ? logit : SLOPE * logit);
    float2 e = *(const float2*)&emb[(size_t)n * OUT_DIM + lane * 2];
    acc.x = sc * e.x;
    acc.y = sc * e.y;
    den = sc;
  }
  const int beg = offset[n];
  const int cnt = deg[n];
  // 2-deep pipelined index/alpha stream: t0/at0 is the edge being consumed,
  // t1 is the next index already in flight.
  int t0 = 0, t1 = 0;
  float at0 = 0.f;
  if (cnt > 0) {
    t0 = __builtin_nontemporal_load(&tsorted[beg]);
    at0 = a2[t0];
  }
  if (cnt > 1) t1 = __builtin_nontemporal_load(&tsorted[beg + 1]);
  for (int e = 0; e < cnt; ++e) {
    // gather current row (longest-latency op, issued first)
    float2 v = *(const float2*)&emb[(size_t)t0 * OUT_DIM + lane * 2];
    float logit = as + at0;
    // advance the pipeline: a2 for t1, index for e+2
    if (e + 1 < cnt) {
      at0 = a2[t1];
      t0 = t1;
      if (e + 2 < cnt) t1 = __builtin_nontemporal_load(&tsorted[beg + e + 2]);
    }
    float sc = expf(logit > 0.f ? logit : SLOPE * logit);
    acc.x += sc * v.x;
    acc.y += sc * v.y;
    den += sc;
  }
  float inv = 1.0f / den;
  float2 o = make_float2(acc.x * inv, acc.y * inv);
  *(float2*)&out[(size_t)n * OUT_DIM + lane * 2] = o;
}

// ---------------------------------------------------------------------------
extern "C" void kernel_launch(void* const* d_in, const int* in_sizes, int n_in,
                              void* d_out, int out_size, void* d_ws,
                              size_t ws_size, hipStream_t stream) {
  const float* node_feats = (const float*)d_in[0];
  const float* W = (const float*)d_in[1];
  const float* bias = (const float*)d_in[2];
  const float* avec = (const float*)d_in[3];
  const int* src = (const int*)d_in[4];
  const int* dst = (const int*)d_in[5];
  float* out = (float*)d_out;

  const int OUT = in_sizes[2];            // 128
  const int IN = in_sizes[1] / OUT;       // 256
  const int N = in_sizes[0] / IN;         // 100000
  const int E = in_sizes[4];              // 1600000

  // Workspace layout (256B-aligned slices). Total ~58.8 MB.
  char* p = (char*)d_ws;
  auto alloc = [&](size_t bytes) {
    void* r = (void*)p;
    p += (bytes + 255) & ~(size_t)255;
    return r;
  };
  float* emb = (float*)alloc((size_t)N * OUT * sizeof(float));   // 51.2 MB
  float* a1 = (float*)alloc((size_t)N * sizeof(float));
  float* a2 = (float*)alloc((size_t)N * sizeof(float));
  int* deg = (int*)alloc((size_t)N * sizeof(int));
  int* offset = (int*)alloc((size_t)N * sizeof(int));
  int* pos = (int*)alloc((size_t)N * sizeof(int));
  int* tsorted = (int*)alloc((size_t)E * sizeof(int));           // 6.4 MB

  hipMemsetAsync(deg, 0, (size_t)N * sizeof(int), stream);

  // CSR histogram is independent of the GEMM; run it first.
  hist_kernel<<<(E + 255) / 256, 256, 0, stream>>>(src, deg, E);

  gemm_kernel<<<(N + BM - 1) / BM, 256, 0, stream>>>(
      node_feats, W, bias, avec, emb, a1, a2, N);

  scan_kernel<<<1, 1024, 0, stream>>>(deg, offset, pos, N);
  scatter_kernel<<<(E + 255) / 256, 256, 0, stream>>>(src, dst, pos, tsorted,
                                                      E);

  aggregate_kernel<<<(N + 3) / 4, 256, 0, stream>>>(emb, a1, a2, offset, deg,
                                                    tsorted, out, N);
}

// Round 4
// 600.859 us; speedup vs baseline: 1.2071x; 1.2071x over previous
//
#include <hip/hip_runtime.h>
#include <hip/hip_bf16.h>

// Problem constants (shapes fixed by the reference; N/E derived at launch).
#define IN_DIM 256
#define OUT_DIM 128
#define SLOPE 0.1f

// ---------------------------------------------------------------------------
// GEMM: emb[N][128] = node_feats[N][256] @ W[128][256]^T + b
// Tile: BM=128 x BN=128, BK=32. 256 threads, 8x8 accumulators each.
// Epilogue fuses a1[r] = emb[r].a[0:128], a2[r] = emb[r].a[128:256].
// ---------------------------------------------------------------------------
#define BM 128
#define BN 128
#define BK 32

__global__ __launch_bounds__(256) void gemm_kernel(
    const float* __restrict__ A,     // [N][256]
    const float* __restrict__ W,     // [128][256]
    const float* __restrict__ bias,  // [128]
    const float* __restrict__ avec,  // [256]
    float* __restrict__ emb,         // [N][128]
    float* __restrict__ a1,          // [N]
    float* __restrict__ a2,          // [N]
    int N) {
  __shared__ float As[BM][BK + 1];
  __shared__ float Bs[BK][BN + 4];

  const int tid = threadIdx.x;
  const int row0 = blockIdx.x * BM;
  const int tx = tid & 15;
  const int ty = tid >> 4;

  float acc[8][8] = {};

  for (int k0 = 0; k0 < IN_DIM; k0 += BK) {
#pragma unroll
    for (int i = 0; i < 4; ++i) {
      int f = tid + i * 256;
      int r = f >> 3;
      int c4 = (f & 7) * 4;
      float4 v = make_float4(0.f, 0.f, 0.f, 0.f);
      if (row0 + r < N)
        v = *(const float4*)&A[(size_t)(row0 + r) * IN_DIM + k0 + c4];
      As[r][c4 + 0] = v.x; As[r][c4 + 1] = v.y;
      As[r][c4 + 2] = v.z; As[r][c4 + 3] = v.w;
    }
#pragma unroll
    for (int i = 0; i < 4; ++i) {
      int f = tid + i * 256;
      int nn = f >> 3;
      int c4 = (f & 7) * 4;
      float4 v = *(const float4*)&W[(size_t)nn * IN_DIM + k0 + c4];
      Bs[c4 + 0][nn] = v.x; Bs[c4 + 1][nn] = v.y;
      Bs[c4 + 2][nn] = v.z; Bs[c4 + 3][nn] = v.w;
    }
    __syncthreads();

#pragma unroll
    for (int k = 0; k < BK; ++k) {
      float a_[8], b_[8];
#pragma unroll
      for (int j = 0; j < 8; ++j) a_[j] = As[ty * 8 + j][k];
#pragma unroll
      for (int i = 0; i < 8; ++i) b_[i] = Bs[k][tx * 8 + i];
#pragma unroll
      for (int j = 0; j < 8; ++j)
#pragma unroll
        for (int i = 0; i < 8; ++i) acc[j][i] += a_[j] * b_[i];
    }
    __syncthreads();
  }

  float p1[8], p2[8];
#pragma unroll
  for (int j = 0; j < 8; ++j) { p1[j] = 0.f; p2[j] = 0.f; }

#pragma unroll
  for (int j = 0; j < 8; ++j) {
    int r = row0 + ty * 8 + j;
    if (r < N) {
#pragma unroll
      for (int i = 0; i < 8; i += 4) {
        int c = tx * 8 + i;
        float4 v;
        v.x = acc[j][i + 0] + bias[c + 0];
        v.y = acc[j][i + 1] + bias[c + 1];
        v.z = acc[j][i + 2] + bias[c + 2];
        v.w = acc[j][i + 3] + bias[c + 3];
        *(float4*)&emb[(size_t)r * OUT_DIM + c] = v;
        p1[j] += v.x * avec[c + 0] + v.y * avec[c + 1] +
                 v.z * avec[c + 2] + v.w * avec[c + 3];
        p2[j] += v.x * avec[OUT_DIM + c + 0] + v.y * avec[OUT_DIM + c + 1] +
                 v.z * avec[OUT_DIM + c + 2] + v.w * avec[OUT_DIM + c + 3];
      }
    }
  }
#pragma unroll
  for (int j = 0; j < 8; ++j) {
#pragma unroll
    for (int d = 1; d < 16; d <<= 1) {
      p1[j] += __shfl_xor(p1[j], d, 64);
      p2[j] += __shfl_xor(p2[j], d, 64);
    }
  }
  if (tx == 0) {
#pragma unroll
    for (int j = 0; j < 8; ++j) {
      int r = row0 + ty * 8 + j;
      if (r < N) { a1[r] = p1[j]; a2[r] = p2[j]; }
    }
  }
}

// ---------------------------------------------------------------------------
// CSR build: histogram, 3-kernel hierarchical exclusive scan, cursor scatter.
// ---------------------------------------------------------------------------
__global__ void hist_kernel(const int* __restrict__ src, int* __restrict__ deg,
                            int E) {
  int i = blockIdx.x * blockDim.x + threadIdx.x;
  if (i < E) atomicAdd(&deg[src[i]], 1);
}

// scan1: per-1024-block exclusive scan of deg -> offset; block totals out.
__global__ __launch_bounds__(1024) void scan1_kernel(
    const int* __restrict__ deg, int* __restrict__ offset,
    int* __restrict__ blocksum, int N) {
  __shared__ int tmp[16];
  const int tid = threadIdx.x;
  const int lane = tid & 63;
  const int wave = tid >> 6;
  int i = blockIdx.x * 1024 + tid;
  int v = (i < N) ? deg[i] : 0;
  int x = v;
#pragma unroll
  for (int d = 1; d < 64; d <<= 1) {
    int y = __shfl_up(x, d, 64);
    if (lane >= d) x += y;
  }
  if (lane == 63) tmp[wave] = x;
  __syncthreads();
  if (tid < 16) {
    int wv = tmp[tid];
#pragma unroll
    for (int d = 1; d < 16; d <<= 1) {
      int y = __shfl_up(wv, d, 16);
      if (tid >= d) wv += y;
    }
    tmp[tid] = wv;  // inclusive wave totals
  }
  __syncthreads();
  int waveoff = (wave == 0) ? 0 : tmp[wave - 1];
  if (i < N) offset[i] = waveoff + x - v;  // block-local exclusive
  if (tid == 0) blocksum[blockIdx.x] = tmp[15];
}

// scan2: single block scans the (<=1024) block sums in place (exclusive).
__global__ __launch_bounds__(1024) void scan2_kernel(int* __restrict__ blocksum,
                                                     int nb) {
  __shared__ int tmp[16];
  const int tid = threadIdx.x;
  const int lane = tid & 63;
  const int wave = tid >> 6;
  int v = (tid < nb) ? blocksum[tid] : 0;
  int x = v;
#pragma unroll
  for (int d = 1; d < 64; d <<= 1) {
    int y = __shfl_up(x, d, 64);
    if (lane >= d) x += y;
  }
  if (lane == 63) tmp[wave] = x;
  __syncthreads();
  if (tid < 16) {
    int wv = tmp[tid];
#pragma unroll
    for (int d = 1; d < 16; d <<= 1) {
      int y = __shfl_up(wv, d, 16);
      if (tid >= d) wv += y;
    }
    tmp[tid] = wv;
  }
  __syncthreads();
  int waveoff = (wave == 0) ? 0 : tmp[wave - 1];
  if (tid < nb) blocksum[tid] = waveoff + x - v;  // exclusive block offsets
}

// scan3: add block offset; replicate into the scatter cursor array.
__global__ void scan3_kernel(int* __restrict__ offset,
                             const int* __restrict__ blocksum,
                             int* __restrict__ pos, int N) {
  int i = blockIdx.x * blockDim.x + threadIdx.x;
  if (i < N) {
    int o = offset[i] + blocksum[i >> 10];
    offset[i] = o;
    pos[i] = o;
  }
}

__global__ void scatter_kernel(const int* __restrict__ src,
                               const int* __restrict__ dst,
                               int* __restrict__ pos,
                               int* __restrict__ tsorted, int E) {
  int i = blockIdx.x * blockDim.x + threadIdx.x;
  if (i < E) {
    int p = atomicAdd(&pos[src[i]], 1);
    tsorted[p] = dst[i];
  }
}

// ---------------------------------------------------------------------------
// Aggregation: one wave per node; 32 lanes (float4 each) cover one 512B emb
// row, so the wave processes TWO items per iteration (half = lane>>5).
// Item 0 is the self-loop; items 1..cnt are CSR edges. Each half-wave
// computes its own score (halves redundant exp/VALU per edge) and the two
// halves' accumulators merge with __shfl_xor(32) at the end.
// ---------------------------------------------------------------------------
__global__ __launch_bounds__(256) void aggregate_kernel(
    const float* __restrict__ emb, const float* __restrict__ a1,
    const float* __restrict__ a2, const int* __restrict__ offset,
    const int* __restrict__ deg, const int* __restrict__ tsorted,
    float* __restrict__ out, int N) {
  int n = (int)((blockIdx.x * (size_t)blockDim.x + threadIdx.x) >> 6);
  int lane = threadIdx.x & 63;
  if (n >= N) return;
  const int half = lane >> 5;
  const int sub = lane & 31;            // covers cols sub*4 .. sub*4+3

  const float as = a1[n];
  const int beg = offset[n];
  const int cnt = deg[n];
  const int items = cnt + 1;            // +1: self loop at item 0
  const int niter = (items + 1) >> 1;

  float4 acc = make_float4(0.f, 0.f, 0.f, 0.f);
  float den = 0.f;

  // Pipelined index/alpha stream; this half consumes items 2*i + half.
  int idx = half;
  int t = (idx == 0 || idx > cnt) ? n : tsorted[beg + idx - 1];
  float at = a2[t];

  for (int i = 0; i < niter; ++i) {
    const bool valid = (idx < items);
    const float4 v = *(const float4*)&emb[(size_t)t * OUT_DIM + sub * 4];
    const float logit = as + at;
    // prefetch next pair's index + alpha while the gather is in flight
    int idxn = idx + 2;
    if (i + 1 < niter) {
      int tn = (idxn <= cnt) ? tsorted[beg + idxn - 1] : n;  // idxn >= 2
      t = tn;
      at = a2[tn];
    }
    idx = idxn;
    float sc = valid ? __expf(logit > 0.f ? logit : SLOPE * logit) : 0.f;
    acc.x += sc * v.x;
    acc.y += sc * v.y;
    acc.z += sc * v.z;
    acc.w += sc * v.w;
    den += sc;
  }

  // merge the two half-wave accumulators
  acc.x += __shfl_xor(acc.x, 32, 64);
  acc.y += __shfl_xor(acc.y, 32, 64);
  acc.z += __shfl_xor(acc.z, 32, 64);
  acc.w += __shfl_xor(acc.w, 32, 64);
  den   += __shfl_xor(den,   32, 64);

  if (half == 0) {
    const float inv = 1.0f / den;
    float4 o = make_float4(acc.x * inv, acc.y * inv, acc.z * inv, acc.w * inv);
    *(float4*)&out[(size_t)n * OUT_DIM + sub * 4] = o;
  }
}

// ---------------------------------------------------------------------------
extern "C" void kernel_launch(void* const* d_in, const int* in_sizes, int n_in,
                              void* d_out, int out_size, void* d_ws,
                              size_t ws_size, hipStream_t stream) {
  const float* node_feats = (const float*)d_in[0];
  const float* W = (const float*)d_in[1];
  const float* bias = (const float*)d_in[2];
  const float* avec = (const float*)d_in[3];
  const int* src = (const int*)d_in[4];
  const int* dst = (const int*)d_in[5];
  float* out = (float*)d_out;

  const int OUT = in_sizes[2];            // 128
  const int IN = in_sizes[1] / OUT;       // 256
  const int N = in_sizes[0] / IN;         // 100000
  const int E = in_sizes[4];              // 1600000
  const int NB = (N + 1023) / 1024;       // scan blocks (98)

  // Workspace layout (256B-aligned slices). Total ~58.8 MB.
  char* p = (char*)d_ws;
  auto alloc = [&](size_t bytes) {
    void* r = (void*)p;
    p += (bytes + 255) & ~(size_t)255;
    return r;
  };
  float* emb = (float*)alloc((size_t)N * OUT * sizeof(float));   // 51.2 MB
  float* a1 = (float*)alloc((size_t)N * sizeof(float));
  float* a2 = (float*)alloc((size_t)N * sizeof(float));
  int* deg = (int*)alloc((size_t)N * sizeof(int));
  int* offset = (int*)alloc((size_t)N * sizeof(int));
  int* pos = (int*)alloc((size_t)N * sizeof(int));
  int* blocksum = (int*)alloc((size_t)NB * sizeof(int));
  int* tsorted = (int*)alloc((size_t)E * sizeof(int));           // 6.4 MB

  hipMemsetAsync(deg, 0, (size_t)N * sizeof(int), stream);

  hist_kernel<<<(E + 255) / 256, 256, 0, stream>>>(src, deg, E);

  gemm_kernel<<<(N + BM - 1) / BM, 256, 0, stream>>>(
      node_feats, W, bias, avec, emb, a1, a2, N);

  scan1_kernel<<<NB, 1024, 0, stream>>>(deg, offset, blocksum, N);
  scan2_kernel<<<1, 1024, 0, stream>>>(blocksum, NB);
  scan3_kernel<<<(N + 255) / 256, 256, 0, stream>>>(offset, blocksum, pos, N);

  scatter_kernel<<<(E + 255) / 256, 256, 0, stream>>>(src, dst, pos, tsorted,
                                                      E);

  aggregate_kernel<<<(N + 3) / 4, 256, 0, stream>>>(emb, a1, a2, offset, deg,
                                                    tsorted, out, N);
}

// Round 5
// 580.524 us; speedup vs baseline: 1.2494x; 1.0350x over previous
//
#include <hip/hip_runtime.h>
#include <hip/hip_bf16.h>

// Problem constants (shapes fixed by the reference; N/E derived at launch).
#define IN_DIM 256
#define OUT_DIM 128
#define SLOPE 0.1f

typedef __attribute__((ext_vector_type(8))) __bf16 bf16x8;
typedef __attribute__((ext_vector_type(4))) float f32x4;

// ---------------------------------------------------------------------------
// W split: Whi/Wlo bf16 [128][256] row-major (K-contiguous) so a B-fragment
// (lane l: n = n0+(l&15), k = k0+8*(l>>4)+j, j=0..7) is one 16B load.
// ---------------------------------------------------------------------------
__global__ void convert_w_kernel(const float* __restrict__ W,
                                 __bf16* __restrict__ Whi,
                                 __bf16* __restrict__ Wlo, int total) {
  int i = blockIdx.x * blockDim.x + threadIdx.x;
  if (i < total) {
    float x = W[i];
    __bf16 h = (__bf16)x;
    __bf16 l = (__bf16)(x - (float)h);
    Whi[i] = h;
    Wlo[i] = l;
  }
}

// ---------------------------------------------------------------------------
// Split-bf16 MFMA GEMM: emb[N][128] = A[N][256] @ W^T + b, fp32-ish accuracy
// via 3 products (hi*hi + hi*lo + lo*hi) accumulated in fp32 MFMA.
// Block: 256 threads = 4 waves; wave w owns rows blk*64 + w*16 (M=16, N=128
// = 8 MFMA tiles of 16x16, K=256 in 8 steps of 32). No LDS, no barriers.
// Epilogue fuses bias add + a1/a2 attention dots.
// ---------------------------------------------------------------------------
__global__ __launch_bounds__(256) void gemm_mfma_kernel(
    const float* __restrict__ A,      // [N][256]
    const __bf16* __restrict__ Whi,   // [128][256]
    const __bf16* __restrict__ Wlo,   // [128][256]
    const float* __restrict__ bias,   // [128]
    const float* __restrict__ avec,   // [256]
    float* __restrict__ emb,          // [N][128]
    float* __restrict__ a1,           // [N]
    float* __restrict__ a2,           // [N]
    int N) {
  const int lane = threadIdx.x & 63;
  const int wave = threadIdx.x >> 6;
  const int m0 = blockIdx.x * 64 + wave * 16;
  const int lr = lane & 15;  // A-row / B-col / C-col within tile
  const int lg = lane >> 4;  // k-group (A/B), row-group (C)

  int arow = m0 + lr;
  if (arow > N - 1) arow = N - 1;  // clamp: loads stay valid, stores guarded
  const float* aptr = A + (size_t)arow * IN_DIM + lg * 8;

  f32x4 acc[8];
#pragma unroll
  for (int t = 0; t < 8; ++t) acc[t] = (f32x4)(0.f);

  for (int k0 = 0; k0 < IN_DIM; k0 += 32) {
    // A fragment: 8 fp32 (lanes of one k-group cover 128 contiguous bytes
    // of each row), converted in-register to hi/lo bf16.
    float4 q0 = *(const float4*)(aptr + k0);
    float4 q1 = *(const float4*)(aptr + k0 + 4);
    float qs[8] = {q0.x, q0.y, q0.z, q0.w, q1.x, q1.y, q1.z, q1.w};
    bf16x8 ahi, alo;
#pragma unroll
    for (int j = 0; j < 8; ++j) {
      float x = qs[j];
      __bf16 h = (__bf16)x;
      ahi[j] = h;
      alo[j] = (__bf16)(x - (float)h);
    }
    const int kcol = k0 + lg * 8;
#pragma unroll
    for (int t = 0; t < 8; ++t) {
      const size_t woff = (size_t)(t * 16 + lr) * IN_DIM + kcol;
      bf16x8 bhi = *(const bf16x8*)(Whi + woff);
      bf16x8 blo = *(const bf16x8*)(Wlo + woff);
      acc[t] = __builtin_amdgcn_mfma_f32_16x16x32_bf16(ahi, bhi, acc[t], 0, 0, 0);
      acc[t] = __builtin_amdgcn_mfma_f32_16x16x32_bf16(ahi, blo, acc[t], 0, 0, 0);
      acc[t] = __builtin_amdgcn_mfma_f32_16x16x32_bf16(alo, bhi, acc[t], 0, 0, 0);
    }
  }

  // Epilogue. C/D layout (m89-verified): col = lane&15, row = (lane>>4)*4+v.
  float p1[4] = {0.f, 0.f, 0.f, 0.f};
  float p2[4] = {0.f, 0.f, 0.f, 0.f};
#pragma unroll
  for (int t = 0; t < 8; ++t) {
    const int c = t * 16 + lr;
    const float bv = bias[c];
    const float av1 = avec[c];
    const float av2 = avec[OUT_DIM + c];
#pragma unroll
    for (int v = 0; v < 4; ++v) {
      const int r = m0 + lg * 4 + v;
      const float e = acc[t][v] + bv;
      if (r < N) emb[(size_t)r * OUT_DIM + c] = e;
      p1[v] += e * av1;
      p2[v] += e * av2;
    }
  }
  // Reduce the 16 lanes sharing a row (xor 1,2,4,8 stays in the 16-group).
#pragma unroll
  for (int v = 0; v < 4; ++v) {
#pragma unroll
    for (int d = 1; d < 16; d <<= 1) {
      p1[v] += __shfl_xor(p1[v], d, 64);
      p2[v] += __shfl_xor(p2[v], d, 64);
    }
  }
  if (lr == 0) {
#pragma unroll
    for (int v = 0; v < 4; ++v) {
      const int r = m0 + lg * 4 + v;
      if (r < N) { a1[r] = p1[v]; a2[r] = p2[v]; }
    }
  }
}

// ---------------------------------------------------------------------------
// CSR build: histogram, 3-kernel hierarchical exclusive scan, cursor scatter.
// ---------------------------------------------------------------------------
__global__ void hist_kernel(const int* __restrict__ src, int* __restrict__ deg,
                            int E) {
  int i = blockIdx.x * blockDim.x + threadIdx.x;
  if (i < E) atomicAdd(&deg[src[i]], 1);
}

__global__ __launch_bounds__(1024) void scan1_kernel(
    const int* __restrict__ deg, int* __restrict__ offset,
    int* __restrict__ blocksum, int N) {
  __shared__ int tmp[16];
  const int tid = threadIdx.x;
  const int lane = tid & 63;
  const int wave = tid >> 6;
  int i = blockIdx.x * 1024 + tid;
  int v = (i < N) ? deg[i] : 0;
  int x = v;
#pragma unroll
  for (int d = 1; d < 64; d <<= 1) {
    int y = __shfl_up(x, d, 64);
    if (lane >= d) x += y;
  }
  if (lane == 63) tmp[wave] = x;
  __syncthreads();
  if (tid < 16) {
    int wv = tmp[tid];
#pragma unroll
    for (int d = 1; d < 16; d <<= 1) {
      int y = __shfl_up(wv, d, 16);
      if (tid >= d) wv += y;
    }
    tmp[tid] = wv;
  }
  __syncthreads();
  int waveoff = (wave == 0) ? 0 : tmp[wave - 1];
  if (i < N) offset[i] = waveoff + x - v;
  if (tid == 0) blocksum[blockIdx.x] = tmp[15];
}

__global__ __launch_bounds__(1024) void scan2_kernel(int* __restrict__ blocksum,
                                                     int nb) {
  __shared__ int tmp[16];
  const int tid = threadIdx.x;
  const int lane = tid & 63;
  const int wave = tid >> 6;
  int v = (tid < nb) ? blocksum[tid] : 0;
  int x = v;
#pragma unroll
  for (int d = 1; d < 64; d <<= 1) {
    int y = __shfl_up(x, d, 64);
    if (lane >= d) x += y;
  }
  if (lane == 63) tmp[wave] = x;
  __syncthreads();
  if (tid < 16) {
    int wv = tmp[tid];
#pragma unroll
    for (int d = 1; d < 16; d <<= 1) {
      int y = __shfl_up(wv, d, 16);
      if (tid >= d) wv += y;
    }
    tmp[tid] = wv;
  }
  __syncthreads();
  int waveoff = (wave == 0) ? 0 : tmp[wave - 1];
  if (tid < nb) blocksum[tid] = waveoff + x - v;
}

__global__ void scan3_kernel(int* __restrict__ offset,
                             const int* __restrict__ blocksum,
                             int* __restrict__ pos, int N) {
  int i = blockIdx.x * blockDim.x + threadIdx.x;
  if (i < N) {
    int o = offset[i] + blocksum[i >> 10];
    offset[i] = o;
    pos[i] = o;
  }
}

__global__ void scatter_kernel(const int* __restrict__ src,
                               const int* __restrict__ dst,
                               int* __restrict__ pos,
                               int* __restrict__ tsorted, int E) {
  int i = blockIdx.x * blockDim.x + threadIdx.x;
  if (i < E) {
    int p = atomicAdd(&pos[src[i]], 1);
    tsorted[p] = dst[i];
  }
}

// ---------------------------------------------------------------------------
// Aggregation: one wave per node; 16 lanes x 32B (two float4) cover one 512B
// emb row, so the wave processes FOUR items per iteration (q = lane>>4).
// Item 0 is the self-loop; items 1..cnt are CSR edges. Each quarter-wave
// computes its own score; quarters merge with xor(16), xor(32) at the end.
// ---------------------------------------------------------------------------
__global__ __launch_bounds__(256) void aggregate_kernel(
    const float* __restrict__ emb, const float* __restrict__ a1,
    const float* __restrict__ a2, const int* __restrict__ offset,
    const int* __restrict__ deg, const int* __restrict__ tsorted,
    float* __restrict__ out, int N) {
  int n = (int)((blockIdx.x * (size_t)blockDim.x + threadIdx.x) >> 6);
  int lane = threadIdx.x & 63;
  if (n >= N) return;
  const int q = lane >> 4;
  const int sub = lane & 15;  // covers cols sub*8 .. sub*8+7

  const float as = a1[n];
  const int beg = offset[n];
  const int cnt = deg[n];
  const int items = cnt + 1;  // +1: self loop at item 0
  const int niter = (items + 3) >> 2;

  float4 acc0 = make_float4(0.f, 0.f, 0.f, 0.f);
  float4 acc1 = make_float4(0.f, 0.f, 0.f, 0.f);
  float den = 0.f;

  // This quarter consumes items idx = 4*i + q. Pipelined index/alpha stream.
  int idx = q;
  int t = (idx == 0 || idx > cnt) ? n : tsorted[beg + idx - 1];
  float at = a2[t];

  for (int i = 0; i < niter; ++i) {
    const bool valid = (idx < items);
    const float* row = emb + (size_t)t * OUT_DIM + sub * 8;
    const float4 v0 = *(const float4*)row;
    const float4 v1 = *(const float4*)(row + 4);
    const float logit = as + at;
    const int idxn = idx + 4;
    if (i + 1 < niter) {
      int tn = (idxn <= cnt) ? tsorted[beg + idxn - 1] : n;  // idxn >= 4
      t = tn;
      at = a2[tn];
    }
    idx = idxn;
    const float sc = valid ? __expf(logit > 0.f ? logit : SLOPE * logit) : 0.f;
    acc0.x += sc * v0.x; acc0.y += sc * v0.y;
    acc0.z += sc * v0.z; acc0.w += sc * v0.w;
    acc1.x += sc * v1.x; acc1.y += sc * v1.y;
    acc1.z += sc * v1.z; acc1.w += sc * v1.w;
    den += sc;
  }

  // Merge the four quarter-wave accumulators (lanes with equal sub).
#pragma unroll
  for (int d = 16; d < 64; d <<= 1) {
    acc0.x += __shfl_xor(acc0.x, d, 64);
    acc0.y += __shfl_xor(acc0.y, d, 64);
    acc0.z += __shfl_xor(acc0.z, d, 64);
    acc0.w += __shfl_xor(acc0.w, d, 64);
    acc1.x += __shfl_xor(acc1.x, d, 64);
    acc1.y += __shfl_xor(acc1.y, d, 64);
    acc1.z += __shfl_xor(acc1.z, d, 64);
    acc1.w += __shfl_xor(acc1.w, d, 64);
    den    += __shfl_xor(den,    d, 64);
  }

  if (q == 0) {
    const float inv = 1.0f / den;
    float* op = out + (size_t)n * OUT_DIM + sub * 8;
    *(float4*)op = make_float4(acc0.x * inv, acc0.y * inv, acc0.z * inv,
                               acc0.w * inv);
    *(float4*)(op + 4) = make_float4(acc1.x * inv, acc1.y * inv, acc1.z * inv,
                                     acc1.w * inv);
  }
}

// ---------------------------------------------------------------------------
extern "C" void kernel_launch(void* const* d_in, const int* in_sizes, int n_in,
                              void* d_out, int out_size, void* d_ws,
                              size_t ws_size, hipStream_t stream) {
  const float* node_feats = (const float*)d_in[0];
  const float* W = (const float*)d_in[1];
  const float* bias = (const float*)d_in[2];
  const float* avec = (const float*)d_in[3];
  const int* src = (const int*)d_in[4];
  const int* dst = (const int*)d_in[5];
  float* out = (float*)d_out;

  const int OUT = in_sizes[2];            // 128
  const int IN = in_sizes[1] / OUT;       // 256
  const int N = in_sizes[0] / IN;         // 100000
  const int E = in_sizes[4];              // 1600000
  const int NB = (N + 1023) / 1024;       // scan blocks (98)
  const int WTOT = in_sizes[1];           // 32768

  // Workspace layout (256B-aligned slices). Total ~59 MB.
  char* p = (char*)d_ws;
  auto alloc = [&](size_t bytes) {
    void* r = (void*)p;
    p += (bytes + 255) & ~(size_t)255;
    return r;
  };
  float* emb = (float*)alloc((size_t)N * OUT * sizeof(float));   // 51.2 MB
  float* a1 = (float*)alloc((size_t)N * sizeof(float));
  float* a2 = (float*)alloc((size_t)N * sizeof(float));
  int* deg = (int*)alloc((size_t)N * sizeof(int));
  int* offset = (int*)alloc((size_t)N * sizeof(int));
  int* pos = (int*)alloc((size_t)N * sizeof(int));
  int* blocksum = (int*)alloc((size_t)NB * sizeof(int));
  int* tsorted = (int*)alloc((size_t)E * sizeof(int));           // 6.4 MB
  __bf16* Whi = (__bf16*)alloc((size_t)WTOT * sizeof(__bf16));   // 64 KB
  __bf16* Wlo = (__bf16*)alloc((size_t)WTOT * sizeof(__bf16));   // 64 KB

  hipMemsetAsync(deg, 0, (size_t)N * sizeof(int), stream);

  convert_w_kernel<<<(WTOT + 255) / 256, 256, 0, stream>>>(W, Whi, Wlo, WTOT);
  hist_kernel<<<(E + 255) / 256, 256, 0, stream>>>(src, deg, E);

  gemm_mfma_kernel<<<(N + 63) / 64, 256, 0, stream>>>(
      node_feats, Whi, Wlo, bias, avec, emb, a1, a2, N);

  scan1_kernel<<<NB, 1024, 0, stream>>>(deg, offset, blocksum, N);
  scan2_kernel<<<1, 1024, 0, stream>>>(blocksum, NB);
  scan3_kernel<<<(N + 255) / 256, 256, 0, stream>>>(offset, blocksum, pos, N);

  scatter_kernel<<<(E + 255) / 256, 256, 0, stream>>>(src, dst, pos, tsorted,
                                                      E);

  aggregate_kernel<<<(N + 3) / 4, 256, 0, stream>>>(emb, a1, a2, offset, deg,
                                                    tsorted, out, N);
}

// Round 6
// 515.819 us; speedup vs baseline: 1.4061x; 1.1254x over previous
//
#include <hip/hip_runtime.h>
#include <hip/hip_bf16.h>

// Problem constants (shapes fixed by the reference; N/E derived at launch).
#define IN_DIM 256
#define OUT_DIM 128
#define SLOPE 0.1f

typedef __attribute__((ext_vector_type(8))) _Float16 f16x8;
typedef __attribute__((ext_vector_type(4))) float f32x4;
typedef __attribute__((ext_vector_type(8))) unsigned short u16x8;

// ---------------------------------------------------------------------------
// W convert: fp32 [128][256] -> f16 [128][256] row-major (K-contiguous).
// f16 rounding (2^-11 rel) contributes ~3e-4 rms to emb - under the 7.8e-3
// error floor observed (which is exp/aggregation-dominated, GEMM-insensitive).
// ---------------------------------------------------------------------------
__global__ void convert_w_kernel(const float* __restrict__ W,
                                 _Float16* __restrict__ Wf, int total) {
  int i = blockIdx.x * blockDim.x + threadIdx.x;
  if (i < total) Wf[i] = (_Float16)W[i];
}

// ---------------------------------------------------------------------------
// Split-f16 MFMA GEMM: emb[N][128] = A[N][256] @ W^T + b.
// A = Ahi + Alo (f16 pair, 22-bit effective mantissa); W single f16.
// 2 MFMA per tile (Ahi*Wf + Alo*Wf), fp32 accumulate.
//
// Block: 256 threads = 4 waves; wave w owns rows blk*64 + w*16.
// Whole Wf (64 KB) staged to LDS once per block with XOR swizzle
// (byte ^= (row&7)<<4): the per-column fragment read would otherwise be a
// 32-way bank conflict (row stride 512B); swizzled it is 2-way (free).
// K-loop: A from global (fp32, converted in-register), B via ds_read_b128.
// Epilogue fuses bias + a1/a2 attention dots.
// ---------------------------------------------------------------------------
__global__ __launch_bounds__(256) void gemm_mfma_kernel(
    const float* __restrict__ A,      // [N][256]
    const _Float16* __restrict__ Wf,  // [128][256]
    const float* __restrict__ bias,   // [128]
    const float* __restrict__ avec,   // [256]
    float* __restrict__ emb,          // [N][128]
    float* __restrict__ a1,           // [N]
    float* __restrict__ a2,           // [N]
    int N) {
  __shared__ _Float16 wlds[32768];    // 64 KB

  const int tid = threadIdx.x;

  // ---- stage Wf -> LDS (swizzled content at linear dest) ----
  // LDS byte f (row n = f>>9, within-row o = f&511) holds global byte
  // n*512 + (o ^ ((n&7)<<4)), so reads at o_r = o_linear ^ ((n&7)<<4)
  // recover the linear element. XOR touches byte bits 4..6 only ->
  // 16B chunks stay contiguous.
#pragma unroll
  for (int i = 0; i < 16; ++i) {
    int chunk = tid + i * 256;        // 4096 chunks of 16B
    int f = chunk << 4;
    int n = f >> 9;
    int o = f & 511;
    int osrc = o ^ ((n & 7) << 4);
    u16x8 v = *(const u16x8*)((const char*)Wf + (size_t)n * 512 + osrc);
    *(u16x8*)((char*)wlds + f) = v;
  }
  __syncthreads();

  const int lane = tid & 63;
  const int wave = tid >> 6;
  const int m0 = blockIdx.x * 64 + wave * 16;
  const int lr = lane & 15;  // A-row / B-col / C-col within tile
  const int kg = lane >> 4;  // k-group (A/B), row-group (C)

  int arow = m0 + lr;
  if (arow > N - 1) arow = N - 1;  // clamp: loads valid, stores guarded
  const float* aptr = A + (size_t)arow * IN_DIM + kg * 8;

  f32x4 acc[8];
#pragma unroll
  for (int t = 0; t < 8; ++t) acc[t] = (f32x4)(0.f);

  const int rowbase = lr * 512;        // B-row byte base (tile adds t*8192)
  const int swzmask = (lr & 7) << 4;

  for (int k0 = 0; k0 < IN_DIM; k0 += 32) {
    // A fragment: 8 fp32, split to hi/lo f16 in-register.
    float4 q0 = *(const float4*)(aptr + k0);
    float4 q1 = *(const float4*)(aptr + k0 + 4);
    float qs[8] = {q0.x, q0.y, q0.z, q0.w, q1.x, q1.y, q1.z, q1.w};
    f16x8 ahi, alo;
#pragma unroll
    for (int j = 0; j < 8; ++j) {
      float x = qs[j];
      _Float16 h = (_Float16)x;
      ahi[j] = h;
      alo[j] = (_Float16)(x - (float)h);
    }
    const int ko = ((k0 * 2 + kg * 16) ^ swzmask);
    const char* wl = (const char*)wlds + rowbase + ko;
#pragma unroll
    for (int t = 0; t < 8; ++t) {
      f16x8 bf = *(const f16x8*)(wl + t * 8192);
      acc[t] = __builtin_amdgcn_mfma_f32_16x16x32_f16(ahi, bf, acc[t], 0, 0, 0);
      acc[t] = __builtin_amdgcn_mfma_f32_16x16x32_f16(alo, bf, acc[t], 0, 0, 0);
    }
  }

  // Epilogue. C/D layout (m89-verified): col = lane&15, row = (lane>>4)*4+v.
  float p1[4] = {0.f, 0.f, 0.f, 0.f};
  float p2[4] = {0.f, 0.f, 0.f, 0.f};
#pragma unroll
  for (int t = 0; t < 8; ++t) {
    const int c = t * 16 + lr;
    const float bv = bias[c];
    const float av1 = avec[c];
    const float av2 = avec[OUT_DIM + c];
#pragma unroll
    for (int v = 0; v < 4; ++v) {
      const int r = m0 + kg * 4 + v;
      const float e = acc[t][v] + bv;
      if (r < N) emb[(size_t)r * OUT_DIM + c] = e;
      p1[v] += e * av1;
      p2[v] += e * av2;
    }
  }
#pragma unroll
  for (int v = 0; v < 4; ++v) {
#pragma unroll
    for (int d = 1; d < 16; d <<= 1) {
      p1[v] += __shfl_xor(p1[v], d, 64);
      p2[v] += __shfl_xor(p2[v], d, 64);
    }
  }
  if (lr == 0) {
#pragma unroll
    for (int v = 0; v < 4; ++v) {
      const int r = m0 + kg * 4 + v;
      if (r < N) { a1[r] = p1[v]; a2[r] = p2[v]; }
    }
  }
}

// ---------------------------------------------------------------------------
// CSR build: histogram, 3-kernel hierarchical exclusive scan, cursor scatter.
// ---------------------------------------------------------------------------
__global__ void hist_kernel(const int* __restrict__ src, int* __restrict__ deg,
                            int E) {
  int i = blockIdx.x * blockDim.x + threadIdx.x;
  if (i < E) atomicAdd(&deg[src[i]], 1);
}

__global__ __launch_bounds__(1024) void scan1_kernel(
    const int* __restrict__ deg, int* __restrict__ offset,
    int* __restrict__ blocksum, int N) {
  __shared__ int tmp[16];
  const int tid = threadIdx.x;
  const int lane = tid & 63;
  const int wave = tid >> 6;
  int i = blockIdx.x * 1024 + tid;
  int v = (i < N) ? deg[i] : 0;
  int x = v;
#pragma unroll
  for (int d = 1; d < 64; d <<= 1) {
    int y = __shfl_up(x, d, 64);
    if (lane >= d) x += y;
  }
  if (lane == 63) tmp[wave] = x;
  __syncthreads();
  if (tid < 16) {
    int wv = tmp[tid];
#pragma unroll
    for (int d = 1; d < 16; d <<= 1) {
      int y = __shfl_up(wv, d, 16);
      if (tid >= d) wv += y;
    }
    tmp[tid] = wv;
  }
  __syncthreads();
  int waveoff = (wave == 0) ? 0 : tmp[wave - 1];
  if (i < N) offset[i] = waveoff + x - v;
  if (tid == 0) blocksum[blockIdx.x] = tmp[15];
}

__global__ __launch_bounds__(1024) void scan2_kernel(int* __restrict__ blocksum,
                                                     int nb) {
  __shared__ int tmp[16];
  const int tid = threadIdx.x;
  const int lane = tid & 63;
  const int wave = tid >> 6;
  int v = (tid < nb) ? blocksum[tid] : 0;
  int x = v;
#pragma unroll
  for (int d = 1; d < 64; d <<= 1) {
    int y = __shfl_up(x, d, 64);
    if (lane >= d) x += y;
  }
  if (lane == 63) tmp[wave] = x;
  __syncthreads();
  if (tid < 16) {
    int wv = tmp[tid];
#pragma unroll
    for (int d = 1; d < 16; d <<= 1) {
      int y = __shfl_up(wv, d, 16);
      if (tid >= d) wv += y;
    }
    tmp[tid] = wv;
  }
  __syncthreads();
  int waveoff = (wave == 0) ? 0 : tmp[wave - 1];
  if (tid < nb) blocksum[tid] = waveoff + x - v;
}

__global__ void scan3_kernel(int* __restrict__ offset,
                             const int* __restrict__ blocksum,
                             int* __restrict__ pos, int N) {
  int i = blockIdx.x * blockDim.x + threadIdx.x;
  if (i < N) {
    int o = offset[i] + blocksum[i >> 10];
    offset[i] = o;
    pos[i] = o;
  }
}

__global__ void scatter_kernel(const int* __restrict__ src,
                               const int* __restrict__ dst,
                               int* __restrict__ pos,
                               int* __restrict__ tsorted, int E) {
  int i = blockIdx.x * blockDim.x + threadIdx.x;
  if (i < E) {
    int p = atomicAdd(&pos[src[i]], 1);
    tsorted[p] = dst[i];
  }
}

// ---------------------------------------------------------------------------
// Aggregation: one wave per node; 16 lanes x 32B cover one 512B emb row ->
// four items per wave-iteration (q = lane>>4). Item 0 = self-loop;
// items 1..cnt = CSR edges. Quarter-waves merge via xor(16), xor(32).
// ---------------------------------------------------------------------------
__global__ __launch_bounds__(256) void aggregate_kernel(
    const float* __restrict__ emb, const float* __restrict__ a1,
    const float* __restrict__ a2, const int* __restrict__ offset,
    const int* __restrict__ deg, const int* __restrict__ tsorted,
    float* __restrict__ out, int N) {
  int n = (int)((blockIdx.x * (size_t)blockDim.x + threadIdx.x) >> 6);
  int lane = threadIdx.x & 63;
  if (n >= N) return;
  const int q = lane >> 4;
  const int sub = lane & 15;  // covers cols sub*8 .. sub*8+7

  const float as = a1[n];
  const int beg = offset[n];
  const int cnt = deg[n];
  const int items = cnt + 1;  // +1: self loop at item 0
  const int niter = (items + 3) >> 2;

  float4 acc0 = make_float4(0.f, 0.f, 0.f, 0.f);
  float4 acc1 = make_float4(0.f, 0.f, 0.f, 0.f);
  float den = 0.f;

  int idx = q;
  int t = (idx == 0 || idx > cnt) ? n : tsorted[beg + idx - 1];
  float at = a2[t];

  for (int i = 0; i < niter; ++i) {
    const bool valid = (idx < items);
    const float* row = emb + (size_t)t * OUT_DIM + sub * 8;
    const float4 v0 = *(const float4*)row;
    const float4 v1 = *(const float4*)(row + 4);
    const float logit = as + at;
    const int idxn = idx + 4;
    if (i + 1 < niter) {
      int tn = (idxn <= cnt) ? tsorted[beg + idxn - 1] : n;  // idxn >= 4
      t = tn;
      at = a2[tn];
    }
    idx = idxn;
    const float sc = valid ? __expf(logit > 0.f ? logit : SLOPE * logit) : 0.f;
    acc0.x += sc * v0.x; acc0.y += sc * v0.y;
    acc0.z += sc * v0.z; acc0.w += sc * v0.w;
    acc1.x += sc * v1.x; acc1.y += sc * v1.y;
    acc1.z += sc * v1.z; acc1.w += sc * v1.w;
    den += sc;
  }

#pragma unroll
  for (int d = 16; d < 64; d <<= 1) {
    acc0.x += __shfl_xor(acc0.x, d, 64);
    acc0.y += __shfl_xor(acc0.y, d, 64);
    acc0.z += __shfl_xor(acc0.z, d, 64);
    acc0.w += __shfl_xor(acc0.w, d, 64);
    acc1.x += __shfl_xor(acc1.x, d, 64);
    acc1.y += __shfl_xor(acc1.y, d, 64);
    acc1.z += __shfl_xor(acc1.z, d, 64);
    acc1.w += __shfl_xor(acc1.w, d, 64);
    den    += __shfl_xor(den,    d, 64);
  }

  if (q == 0) {
    const float inv = 1.0f / den;
    float* op = out + (size_t)n * OUT_DIM + sub * 8;
    *(float4*)op = make_float4(acc0.x * inv, acc0.y * inv, acc0.z * inv,
                               acc0.w * inv);
    *(float4*)(op + 4) = make_float4(acc1.x * inv, acc1.y * inv, acc1.z * inv,
                                     acc1.w * inv);
  }
}

// ---------------------------------------------------------------------------
extern "C" void kernel_launch(void* const* d_in, const int* in_sizes, int n_in,
                              void* d_out, int out_size, void* d_ws,
                              size_t ws_size, hipStream_t stream) {
  const float* node_feats = (const float*)d_in[0];
  const float* W = (const float*)d_in[1];
  const float* bias = (const float*)d_in[2];
  const float* avec = (const float*)d_in[3];
  const int* src = (const int*)d_in[4];
  const int* dst = (const int*)d_in[5];
  float* out = (float*)d_out;

  const int OUT = in_sizes[2];            // 128
  const int IN = in_sizes[1] / OUT;       // 256
  const int N = in_sizes[0] / IN;         // 100000
  const int E = in_sizes[4];              // 1600000
  const int NB = (N + 1023) / 1024;       // scan blocks (98)
  const int WTOT = in_sizes[1];           // 32768

  // Workspace layout (256B-aligned slices). Total ~59 MB.
  char* p = (char*)d_ws;
  auto alloc = [&](size_t bytes) {
    void* r = (void*)p;
    p += (bytes + 255) & ~(size_t)255;
    return r;
  };
  float* emb = (float*)alloc((size_t)N * OUT * sizeof(float));   // 51.2 MB
  float* a1 = (float*)alloc((size_t)N * sizeof(float));
  float* a2 = (float*)alloc((size_t)N * sizeof(float));
  int* deg = (int*)alloc((size_t)N * sizeof(int));
  int* offset = (int*)alloc((size_t)N * sizeof(int));
  int* pos = (int*)alloc((size_t)N * sizeof(int));
  int* blocksum = (int*)alloc((size_t)NB * sizeof(int));
  int* tsorted = (int*)alloc((size_t)E * sizeof(int));           // 6.4 MB
  _Float16* Wfp = (_Float16*)alloc((size_t)WTOT * sizeof(_Float16));

  hipMemsetAsync(deg, 0, (size_t)N * sizeof(int), stream);

  convert_w_kernel<<<(WTOT + 255) / 256, 256, 0, stream>>>(W, Wfp, WTOT);
  hist_kernel<<<(E + 255) / 256, 256, 0, stream>>>(src, deg, E);

  gemm_mfma_kernel<<<(N + 63) / 64, 256, 0, stream>>>(
      node_feats, Wfp, bias, avec, emb, a1, a2, N);

  scan1_kernel<<<NB, 1024, 0, stream>>>(deg, offset, blocksum, N);
  scan2_kernel<<<1, 1024, 0, stream>>>(blocksum, NB);
  scan3_kernel<<<(N + 255) / 256, 256, 0, stream>>>(offset, blocksum, pos, N);

  scatter_kernel<<<(E + 255) / 256, 256, 0, stream>>>(src, dst, pos, tsorted,
                                                      E);

  aggregate_kernel<<<(N + 3) / 4, 256, 0, stream>>>(emb, a1, a2, offset, deg,
                                                    tsorted, out, N);
}